// Round 17
// baseline (243.666 us; speedup 1.0000x reference)
//
#include <hip/hip_runtime.h>
#include <hip/hip_bf16.h>

#define INF_F (__builtin_inff())

typedef __attribute__((ext_vector_type(8))) short bf16x8;
typedef __attribute__((ext_vector_type(4))) float f32x4;

__device__ __forceinline__ unsigned short f2bf(float f) {
  __hip_bfloat16 h = __float2bfloat16(f);
  return __builtin_bit_cast(unsigned short, h);
}
__device__ __forceinline__ float bf2f(unsigned short u) {
  return __uint_as_float((unsigned)u << 16);
}

// branchy sorted top-3 insert (scalar state only - R8 lesson: nothing
// address-taken). Strict < + ascending s = top_k lowest-index tie order.
#define TOP3_INS(d, sj, E0, E1, E2, J0, J1, J2)                      \
  {                                                                  \
    bool l0 = (d) < E0, l1 = (d) < E1;                               \
    E2 = l1 ? E1 : (d); J2 = l1 ? J1 : (sj);                         \
    E1 = l0 ? E0 : (l1 ? (d) : E1); J1 = l0 ? J0 : (l1 ? (sj) : J1); \
    E0 = l0 ? (d) : E0; J0 = l0 ? (sj) : J0;                         \
  }

// ---------------------------------------------------------------------------
// B=4, N=16384, S=4096, D1=128, D2=256, MLP=(256,128). M = B*N = 65536.
// X: [65536][384] bf16 ; h1T: [65536][256] bf16 ; o2: [65536][128] bf16.
// GEMMs: D[c][n] = W[c][k] * X[n][k] via mfma_f32_16x16x32_bf16.
// R17: knn slices 8->4 via 128-thread blocks (2048 blocks = 512 qchunks x
// 4 slices of 1024 src; 16 wg/CU x 2 waves = 32 waves/CU). Insert-taken
// rate is per-WAVE (64 states) so halving slices cuts warmup re-runs:
// taken-steps 3040->2052 per wave, -20% VALU. T14 prep overlap kept.
// ---------------------------------------------------------------------------

// pack sources (knn's only dependency) + zero BN stats accumulators.
// pack: [B][4096] float4 {x,y,z,|p|^2 or 3e38 if batch-id mismatch}.
__global__ __launch_bounds__(256) void pack_k(const float* __restrict__ xyz2,
                                              const int* __restrict__ idx1,
                                              const int* __restrict__ idx2,
                                              float4* __restrict__ pack,
                                              float* __restrict__ stats) {
  int id = blockIdx.x;
  int t = threadIdx.x;
  if (id < 64) {
    int pid = id * 256 + t;
    int b = pid >> 12, s = pid & 4095;
    float x = xyz2[(b * 3 + 0) * 4096 + s];
    float y = xyz2[(b * 3 + 1) * 4096 + s];
    float z = xyz2[(b * 3 + 2) * 4096 + s];
    float w = fmaf(x, x, fmaf(y, y, z * z));
    int common = idx1[b * 16384];
    w = (idx2[b * 4096 + s] == common) ? w : 3e38f;  // invalid -> wgt 0
    pack[b * 4096 + s] = make_float4(x, y, z, w);
  } else {
    for (int i = t; i < 768; i += 256) stats[i] = 0.f;
  }
}

// 3-NN stage 1 + T14-overlapped prep. 2048 blocks x 128 thr.
__global__ __launch_bounds__(128) void knnprep_k(const float* __restrict__ xyz1,
                                                 const float* __restrict__ xyz2,
                                                 const int* __restrict__ idx1,
                                                 const int* __restrict__ idx2,
                                                 const float4* __restrict__ pack,
                                                 const float* __restrict__ p2,
                                                 const float* __restrict__ p1,
                                                 const float* __restrict__ w1,
                                                 const float* __restrict__ w2,
                                                 unsigned short* __restrict__ p2t,
                                                 unsigned short* __restrict__ X,
                                                 unsigned short* __restrict__ w1b,
                                                 unsigned short* __restrict__ w2b,
                                                 float* __restrict__ rec) {
  __shared__ float tile[32][33];
  int bid = blockIdx.x;
  int t = threadIdx.x;
  int tx = t & 31, ty4 = t >> 5;  // 32 x 4
  // --- T14 stage A: ISSUE prep loads (no use -> no wait until stage C) ---
  float wv = 0.f;
  if (bid < 1024) {  // 1024 blocks x 128 thr = 131072 weight elems
    int id3 = bid * 128 + t;
    wv = (id3 < 98304) ? w1[id3] : w2[id3 - 98304];
  }
  float t2r[2][8];  // 2 p2 tiles x 8 rows/thread
#pragma unroll
  for (int q = 0; q < 2; ++q) {
    int id = bid * 2 + q;
    int s0 = (id & 127) * 32;
    int k0 = ((id >> 7) & 7) * 32;
    int b = id >> 10;
    const float* src = p2 + ((size_t)b * 256 + k0) * 4096 + s0;
#pragma unroll
    for (int r4 = 0; r4 < 8; ++r4)
      t2r[q][r4] = src[(size_t)(ty4 + r4 * 4) * 4096 + tx];
  }
  float t1r[4][8];  // 4 p1 tiles x 8 rows/thread
#pragma unroll
  for (int q = 0; q < 4; ++q) {
    int id2 = bid * 4 + q;
    int n0 = (id2 & 511) * 32;
    int c0 = ((id2 >> 9) & 3) * 32;
    int b = id2 >> 11;
    const float* src = p1 + ((size_t)b * 128 + c0) * 16384 + n0;
#pragma unroll
    for (int r4 = 0; r4 < 8; ++r4)
      t1r[q][r4] = src[(size_t)(ty4 + r4 * 4) * 16384 + tx];
  }
  // --- T14 stage B: knn (VALU + s_load/lgkmcnt; vmem loads stay in flight) ---
  int qg = bid >> 2, sl = bid & 3;
  int b = qg >> 7;               // 128 query-chunks per batch (128 q each)
  int nloc = (qg & 127) << 7;    // query base within batch
  int n = nloc + t;
  int q0i = b * 16384 + n;
  int common = idx1[b * 16384];
  int sbase = sl << 10;          // 1024-source slice
  const float4* ps = pack + b * 4096 + sbase;
  float px = xyz1[(b * 3 + 0) * 16384 + n];
  float py = xyz1[(b * 3 + 1) * 16384 + n];
  float pz = xyz1[(b * 3 + 2) * 16384 + n];
  int myid = idx1[q0i];
  float pn = fmaf(px, px, fmaf(py, py, pz * pz));
  float qx = -2.f * px, qy = -2.f * py, qz = -2.f * pz;
  float e0 = INF_F, e1 = INF_F, e2 = INF_F;
  int j0 = 0, j1 = 0, j2 = 0;
#pragma unroll 8
  for (int s = 0; s < 1024; ++s) {
    float4 p = ps[s];  // uniform addr -> scalar load (s_load_dwordx4/x16)
    float d = fmaf(qx, p.x, fmaf(qy, p.y, fmaf(qz, p.z, pn))) + p.w;
    if (__builtin_expect(d < e2, 0)) {  // 64 states/wave: genuinely skippable
      int sj = sbase + s;
      TOP3_INS(d, sj, e0, e1, e2, j0, j1, j2);
    }
  }
  if (__builtin_expect(myid != common, 0)) {  // exact general-idx fallback
    e0 = INF_F; e1 = INF_F; e2 = INF_F; j0 = 0; j1 = 0; j2 = 0;
    for (int s = 0; s < 1024; ++s) {
      int gs = sbase + s;
      float x = xyz2[(b * 3 + 0) * 4096 + gs];
      float y = xyz2[(b * 3 + 1) * 4096 + gs];
      float z = xyz2[(b * 3 + 2) * 4096 + gs];
      float w = fmaf(x, x, fmaf(y, y, z * z));
      float d = fmaf(qx, x, fmaf(qy, y, fmaf(qz, z, pn))) + w;
      d = (idx2[b * 4096 + gs] == myid) ? d : INF_F;
      if (d < e2) TOP3_INS(d, gs, e0, e1, e2, j0, j1, j2);
    }
  }
  // rec layout [slice][query]: lane-consecutive 24B records => coalesced
  {
    float* r = &rec[((size_t)sl * 65536 + q0i) * 6];
    r[0] = e0; r[1] = e1; r[2] = e2;
    ((int*)r)[3] = j0; ((int*)r)[4] = j1; ((int*)r)[5] = j2;
  }
  // --- T14 stage C: write-late (vmcnt drains here; loads completed under B) ---
  if (bid < 1024) {
    int id3 = bid * 128 + t;
    if (id3 < 98304) w1b[id3] = f2bf(wv);
    else w2b[id3 - 98304] = f2bf(wv);
  }
#pragma unroll
  for (int q = 0; q < 2; ++q) {
    int id = bid * 2 + q;
    int s0 = (id & 127) * 32;
    int k0 = ((id >> 7) & 7) * 32;
    int bb = id >> 10;
    __syncthreads();
#pragma unroll
    for (int r4 = 0; r4 < 8; ++r4) tile[ty4 + r4 * 4][tx] = t2r[q][r4];
    __syncthreads();
    unsigned short* dst = p2t + ((size_t)bb * 4096 + s0) * 256 + k0;
    for (int r = ty4; r < 32; r += 4) dst[(size_t)r * 256 + tx] = f2bf(tile[tx][r]);
  }
#pragma unroll
  for (int q = 0; q < 4; ++q) {
    int id2 = bid * 4 + q;
    int n0 = (id2 & 511) * 32;
    int c0 = ((id2 >> 9) & 3) * 32;
    int bb = id2 >> 11;
    __syncthreads();
#pragma unroll
    for (int r4 = 0; r4 < 8; ++r4) tile[ty4 + r4 * 4][tx] = t1r[q][r4];
    __syncthreads();
    for (int r = ty4; r < 32; r += 4)
      X[((size_t)(bb * 16384 + n0 + r)) * 384 + c0 + tx] = f2bf(tile[tx][r]);
  }
}

// fused: merge 4 S-slice records (lex (d,idx), ascending slice order = exact
// top_k ties) + inverse-distance weights + gather-interpolate into X.
// 512 blocks x 256 thr; block = 128 queries.
__global__ __launch_bounds__(256) void interpm_k(const float* __restrict__ rec,
                                                 const unsigned short* __restrict__ p2t,
                                                 unsigned short* __restrict__ X) {
  __shared__ int sId[128][3];
  __shared__ float sWt[128][3];
  int i0 = blockIdx.x * 128;
  int b = i0 >> 14;
  int t = threadIdx.x;
  if (t < 128) {
    int i = i0 + t;
    float e0, e1, e2;
    int j0, j1, j2;
    {
      const float* r = &rec[(size_t)i * 6];
      e0 = r[0]; e1 = r[1]; e2 = r[2];
      j0 = ((const int*)r)[3]; j1 = ((const int*)r)[4]; j2 = ((const int*)r)[5];
    }
#pragma unroll
    for (int c = 1; c < 4; ++c) {
      const float* r = &rec[((size_t)c * 65536 + i) * 6];
      const int* ir = (const int*)r;
#pragma unroll
      for (int w = 0; w < 3; ++w) {
        float d = r[w];
        int sj = ir[3 + w];
        bool l0 = (d < e0) || (d == e0 && sj < j0);
        bool l1 = (d < e1) || (d == e1 && sj < j1);
        bool l2 = (d < e2) || (d == e2 && sj < j2);
        e2 = l1 ? e1 : (l2 ? d : e2);
        j2 = l1 ? j1 : (l2 ? sj : j2);
        e1 = l0 ? e0 : (l1 ? d : e1);
        j1 = l0 ? j0 : (l1 ? sj : j1);
        e0 = l0 ? d : e0;
        j0 = l0 ? sj : j0;
      }
    }
    float r0 = 1.f / (e0 + 1e-8f);
    float r1 = 1.f / (e1 + 1e-8f);
    float r2 = 1.f / (e2 + 1e-8f);
    float rs = r0 + r1 + r2;
    sWt[t][0] = (e0 > 1e8f) ? 0.f : r0 / rs;  // ref: where(d3>BIG,0)+nan_to_num
    sWt[t][1] = (e1 > 1e8f) ? 0.f : r1 / rs;
    sWt[t][2] = (e2 > 1e8f) ? 0.f : r2 / rs;
    sId[t][0] = j0; sId[t][1] = j1; sId[t][2] = j2;
  }
  __syncthreads();
  int k = t;
  const unsigned short* base = p2t + (size_t)b * 4096 * 256;
#pragma unroll 2
  for (int ii = 0; ii < 128; ++ii) {
    int id0 = sId[ii][0], id1 = sId[ii][1], id2 = sId[ii][2];
    float w0 = sWt[ii][0], w1v = sWt[ii][1], w2v = sWt[ii][2];
    float v = w0 * bf2f(base[id0 * 256 + k]);
    v = fmaf(w1v, bf2f(base[id1 * 256 + k]), v);
    v = fmaf(w2v, bf2f(base[id2 * 256 + k]), v);
    X[(size_t)(i0 + ii) * 384 + 128 + k] = f2bf(v);
  }
}

// GEMM1 (MFMA): h1T[n][c] = sum_k w1[c][k] X[n][k]. 128x128 tile, BK=32,
// K=384. grid (512, 2). Epilogue: per-block BN1 stats (sum,sumsq per
// channel over block's 128 n) from fp32 acc -> atomicAdd into stats1[256][2].
__global__ __launch_bounds__(256) void gemm1_k(const unsigned short* __restrict__ X,
                                               const unsigned short* __restrict__ Wb,
                                               unsigned short* __restrict__ h1T,
                                               float* __restrict__ stats1) {
  __shared__ unsigned short sW[128][40];
  __shared__ unsigned short sX[128][40];
  int t = threadIdx.x;
  int i0 = blockIdx.x * 128;
  int c0 = blockIdx.y * 128;
  int w = t >> 6, lane = t & 63;
  int wc = (w & 1) * 64, wni = w >> 1;
  int wn = wni * 64;
  int l15 = lane & 15, g = lane >> 4;
  f32x4 acc[4][4];
#pragma unroll
  for (int a = 0; a < 4; ++a)
#pragma unroll
    for (int bq = 0; bq < 4; ++bq) acc[a][bq] = (f32x4)0.f;
  int sr = t & 127, sh = t >> 7;
  for (int kc = 0; kc < 12; ++kc) {
    int k0 = kc * 32;
    __syncthreads();
    {
      const uint4* gw = (const uint4*)&Wb[(size_t)(c0 + sr) * 384 + k0 + sh * 16];
      uint4 v0 = gw[0], v1 = gw[1];
      *(uint4*)&sW[sr][sh * 16] = v0;
      *(uint4*)&sW[sr][sh * 16 + 8] = v1;
      const uint4* gx = (const uint4*)&X[(size_t)(i0 + sr) * 384 + k0 + sh * 16];
      uint4 x0 = gx[0], x1 = gx[1];
      *(uint4*)&sX[sr][sh * 16] = x0;
      *(uint4*)&sX[sr][sh * 16 + 8] = x1;
    }
    __syncthreads();
    bf16x8 a[4], b[4];
#pragma unroll
    for (int tm = 0; tm < 4; ++tm)
      a[tm] = *(const bf16x8*)&sW[wc + tm * 16 + l15][g * 8];
#pragma unroll
    for (int tn = 0; tn < 4; ++tn)
      b[tn] = *(const bf16x8*)&sX[wn + tn * 16 + l15][g * 8];
#pragma unroll
    for (int tm = 0; tm < 4; ++tm)
#pragma unroll
      for (int tn = 0; tn < 4; ++tn)
        acc[tm][tn] = __builtin_amdgcn_mfma_f32_16x16x32_bf16(a[tm], b[tn], acc[tm][tn], 0, 0, 0);
  }
#pragma unroll
  for (int tm = 0; tm < 4; ++tm)
#pragma unroll
    for (int tn = 0; tn < 4; ++tn) {
      int c = c0 + wc + tm * 16 + g * 4;
      int n = i0 + wn + tn * 16 + l15;
      f32x4 v = acc[tm][tn];
      ushort4 o;
      o.x = f2bf(v[0]); o.y = f2bf(v[1]); o.z = f2bf(v[2]); o.w = f2bf(v[3]);
      *(ushort4*)&h1T[(size_t)n * 256 + c] = o;
    }
  // --- fused BN1 stats (fp32 acc) -> atomicAdd ---
  float s_[4][4], q_[4][4];
#pragma unroll
  for (int tm = 0; tm < 4; ++tm)
#pragma unroll
    for (int j = 0; j < 4; ++j) {
      float s = 0.f, q = 0.f;
#pragma unroll
      for (int tn = 0; tn < 4; ++tn) {
        float v = acc[tm][tn][j];
        s += v; q = fmaf(v, v, q);
      }
      s_[tm][j] = s; q_[tm][j] = q;
    }
#pragma unroll
  for (int mask = 1; mask < 16; mask <<= 1)
#pragma unroll
    for (int tm = 0; tm < 4; ++tm)
#pragma unroll
      for (int j = 0; j < 4; ++j) {
        s_[tm][j] += __shfl_xor(s_[tm][j], mask);
        q_[tm][j] += __shfl_xor(q_[tm][j], mask);
      }
  __syncthreads();                 // LDS reuse: sW as float red[2][128][2]
  float* red = (float*)&sW[0][0];
  if (l15 == 0) {
#pragma unroll
    for (int tm = 0; tm < 4; ++tm)
#pragma unroll
      for (int j = 0; j < 4; ++j) {
        int cl = wc + tm * 16 + g * 4 + j;
        red[(wni * 128 + cl) * 2 + 0] = s_[tm][j];
        red[(wni * 128 + cl) * 2 + 1] = q_[tm][j];
      }
  }
  __syncthreads();
  {
    int cl = t >> 1, st = t & 1;
    float v = red[(0 * 128 + cl) * 2 + st] + red[(1 * 128 + cl) * 2 + st];
    atomicAdd(&stats1[((c0 + cl) << 1) + st], v);
  }
}

// GEMM2 (MFMA). Prologue: fold stats1 -> per-channel BN1 a/c in LDS.
// Staging: BN1+relu fused. Epilogue: bf16 o2 write + BN2 stats atomicAdd.
__global__ __launch_bounds__(256) void gemm2_k(const unsigned short* __restrict__ h1T,
                                               const unsigned short* __restrict__ Wb,
                                               const float* __restrict__ stats1,
                                               const float* __restrict__ g1,
                                               const float* __restrict__ be1,
                                               unsigned short* __restrict__ o2,
                                               float* __restrict__ stats2) {
  __shared__ unsigned short sW[128][40];
  __shared__ unsigned short sX[128][40];
  __shared__ float sA1[256], sC1[256];
  int t = threadIdx.x;
  int i0 = blockIdx.x * 128;
  int w = t >> 6, lane = t & 63;
  int wc = (w & 1) * 64, wni = w >> 1;
  int wn = wni * 64;
  int l15 = lane & 15, g = lane >> 4;
  {  // fold BN1 (redundant per block; 256 ch, trivial)
    float s1v = stats1[t * 2 + 0], s2v = stats1[t * 2 + 1];
    float mean = s1v * (1.f / 65536.f);
    float var = s2v * (1.f / 65536.f) - mean * mean;  // biased, as torch BN
    float a = g1[t] * rsqrtf(var + 1e-5f);
    sA1[t] = a;
    sC1[t] = be1[t] - mean * a;
  }
  f32x4 acc[4][4];
#pragma unroll
  for (int a = 0; a < 4; ++a)
#pragma unroll
    for (int bq = 0; bq < 4; ++bq) acc[a][bq] = (f32x4)0.f;
  int sr = t & 127, sh = t >> 7;
  for (int kc = 0; kc < 8; ++kc) {
    int k0 = kc * 32;
    int kcol = k0 + sh * 16;
    __syncthreads();  // also covers prologue->staging dependency at kc=0
    {
      const uint4* gw = (const uint4*)&Wb[(size_t)sr * 256 + kcol];
      uint4 v0 = gw[0], v1 = gw[1];
      *(uint4*)&sW[sr][sh * 16] = v0;
      *(uint4*)&sW[sr][sh * 16 + 8] = v1;
      const uint4* gx = (const uint4*)&h1T[(size_t)(i0 + sr) * 256 + kcol];
      uint4 x0 = gx[0], x1 = gx[1];
      unsigned rr[8] = {x0.x, x0.y, x0.z, x0.w, x1.x, x1.y, x1.z, x1.w};
      unsigned ww[8];
#pragma unroll
      for (int e = 0; e < 8; ++e) {  // BN1+relu fused while staging
        int ch = kcol + 2 * e;
        float f0 = bf2f((unsigned short)(rr[e] & 0xFFFFu));
        float f1 = bf2f((unsigned short)(rr[e] >> 16));
        f0 = fmaxf(fmaf(sA1[ch], f0, sC1[ch]), 0.f);
        f1 = fmaxf(fmaf(sA1[ch + 1], f1, sC1[ch + 1]), 0.f);
        ww[e] = (unsigned)f2bf(f0) | ((unsigned)f2bf(f1) << 16);
      }
      uint4 y0 = {ww[0], ww[1], ww[2], ww[3]};
      uint4 y1 = {ww[4], ww[5], ww[6], ww[7]};
      *(uint4*)&sX[sr][sh * 16] = y0;
      *(uint4*)&sX[sr][sh * 16 + 8] = y1;
    }
    __syncthreads();
    bf16x8 a[4], b[4];
#pragma unroll
    for (int tm = 0; tm < 4; ++tm)
      a[tm] = *(const bf16x8*)&sW[wc + tm * 16 + l15][g * 8];
#pragma unroll
    for (int tn = 0; tn < 4; ++tn)
      b[tn] = *(const bf16x8*)&sX[wn + tn * 16 + l15][g * 8];
#pragma unroll
    for (int tm = 0; tm < 4; ++tm)
#pragma unroll
      for (int tn = 0; tn < 4; ++tn)
        acc[tm][tn] = __builtin_amdgcn_mfma_f32_16x16x32_bf16(a[tm], b[tn], acc[tm][tn], 0, 0, 0);
  }
#pragma unroll
  for (int tm = 0; tm < 4; ++tm)
#pragma unroll
    for (int tn = 0; tn < 4; ++tn) {
      int c = wc + tm * 16 + g * 4;
      int n = i0 + wn + tn * 16 + l15;
      f32x4 v = acc[tm][tn];
      ushort4 o;
      o.x = f2bf(v[0]); o.y = f2bf(v[1]); o.z = f2bf(v[2]); o.w = f2bf(v[3]);
      *(ushort4*)&o2[(size_t)n * 128 + c] = o;
    }
  // --- fused BN2 stats (fp32 acc) -> atomicAdd ---
  float s_[4][4], q_[4][4];
#pragma unroll
  for (int tm = 0; tm < 4; ++tm)
#pragma unroll
    for (int j = 0; j < 4; ++j) {
      float s = 0.f, q = 0.f;
#pragma unroll
      for (int tn = 0; tn < 4; ++tn) {
        float v = acc[tm][tn][j];
        s += v; q = fmaf(v, v, q);
      }
      s_[tm][j] = s; q_[tm][j] = q;
    }
#pragma unroll
  for (int mask = 1; mask < 16; mask <<= 1)
#pragma unroll
    for (int tm = 0; tm < 4; ++tm)
#pragma unroll
      for (int j = 0; j < 4; ++j) {
        s_[tm][j] += __shfl_xor(s_[tm][j], mask);
        q_[tm][j] += __shfl_xor(q_[tm][j], mask);
      }
  __syncthreads();
  float* red = (float*)&sW[0][0];  // [2][128][2]
  if (l15 == 0) {
#pragma unroll
    for (int tm = 0; tm < 4; ++tm)
#pragma unroll
      for (int j = 0; j < 4; ++j) {
        int cl = wc + tm * 16 + g * 4 + j;
        red[(wni * 128 + cl) * 2 + 0] = s_[tm][j];
        red[(wni * 128 + cl) * 2 + 1] = q_[tm][j];
      }
  }
  __syncthreads();
  {
    int cl = t >> 1, st = t & 1;
    float v = red[(0 * 128 + cl) * 2 + st] + red[(1 * 128 + cl) * 2 + st];
    atomicAdd(&stats2[(cl << 1) + st], v);
  }
}

// final: fold stats2 -> BN2 a/c, apply + relu, transpose o2 bf16 [i][128]
// -> d_out [B][128][16384] fp32.
__global__ __launch_bounds__(256) void final_k(const unsigned short* __restrict__ o2,
                                               const float* __restrict__ stats2,
                                               const float* __restrict__ g2,
                                               const float* __restrict__ be2,
                                               float* __restrict__ out) {
  __shared__ float tile[32][33];
  __shared__ float sA2[128], sC2[128];
  int b = blockIdx.z;
  int n0 = blockIdx.x * 32;
  int c0 = blockIdx.y * 32;
  int tx = threadIdx.x, ty = threadIdx.y;
  int tid = ty * 32 + tx;
  if (tid < 128) {  // fold BN2 (redundant per block; 128 ch, trivial)
    float s1v = stats2[tid * 2 + 0], s2v = stats2[tid * 2 + 1];
    float mean = s1v * (1.f / 65536.f);
    float var = s2v * (1.f / 65536.f) - mean * mean;  // biased, as torch BN
    float a = g2[tid] * rsqrtf(var + 1e-5f);
    sA2[tid] = a;
    sC2[tid] = be2[tid] - mean * a;
  }
  __syncthreads();
  float a = sA2[c0 + tx], cc = sC2[c0 + tx];
  for (int r = ty; r < 32; r += 8) {
    float v = bf2f(o2[(size_t)(b * 16384 + n0 + r) * 128 + c0 + tx]);
    tile[r][tx] = fmaxf(fmaf(a, v, cc), 0.f);
  }
  __syncthreads();
  for (int r = ty; r < 32; r += 8)
    out[((size_t)(b * 128 + c0 + r)) * 16384 + n0 + tx] = tile[tx][r];
}

extern "C" void kernel_launch(void* const* d_in, const int* in_sizes, int n_in,
                              void* d_out, int out_size, void* d_ws, size_t ws_size,
                              hipStream_t stream) {
  const float* xyz1 = (const float*)d_in[0];
  const float* xyz2 = (const float*)d_in[1];
  const float* p1   = (const float*)d_in[2];
  const float* p2   = (const float*)d_in[3];
  const int*   idx1 = (const int*)d_in[4];
  const int*   idx2 = (const int*)d_in[5];
  const float* w1   = (const float*)d_in[6];
  // d_in[7]=b1, d_in[11]=b2: exactly absorbed by BN mean subtraction
  const float* g1   = (const float*)d_in[8];
  const float* be1  = (const float*)d_in[9];
  const float* w2   = (const float*)d_in[10];
  const float* g2   = (const float*)d_in[12];
  const float* be2  = (const float*)d_in[13];
  float* out = (float*)d_out;

  char* ws = (char*)d_ws;
  // X 48MB | h1T 32MB (p2t bf16 8.4MB aliased: dead before gemm1 writes)
  // | o2 bf16 16MB (rec 6.3MB aliased: dead before gemm2 writes) | w1b w2b
  // | pack 262KB | stats 3KB  => ~98MB
  unsigned short* X    = (unsigned short*)(ws + 0x180000);      // 48MB
  unsigned short* h1T  = (unsigned short*)(ws + 0x3180000);     // 32MB
  unsigned short* p2t  = (unsigned short*)(ws + 0x3180000);     // alias h1T
  unsigned short* o2   = (unsigned short*)(ws + 0x5180000);     // 16MB
  float*          rec  = (float*)(ws + 0x5180000);              // alias o2
  unsigned short* w1b  = (unsigned short*)(ws + 0x7180000);
  unsigned short* w2b  = (unsigned short*)(ws + 0x71B0000);
  float4*         pack = (float4*)(ws + 0x71C0000);             // 262KB
  float*          stats = (float*)(ws + 0x7208000);             // 768 floats
  float*          stats1 = stats;                               // [256][2]
  float*          stats2 = stats + 512;                         // [128][2]

  hipLaunchKernelGGL(pack_k, dim3(65), dim3(256), 0, stream,
                     xyz2, idx1, idx2, pack, stats);
  hipLaunchKernelGGL(knnprep_k, dim3(2048), dim3(128), 0, stream,
                     xyz1, xyz2, idx1, idx2, pack, p2, p1, w1, w2,
                     p2t, X, w1b, w2b, rec);
  hipLaunchKernelGGL(interpm_k, dim3(512), dim3(256), 0, stream, rec, p2t, X);
  hipLaunchKernelGGL(gemm1_k, dim3(512, 2), dim3(256), 0, stream, X, w1b, h1T, stats1);
  hipLaunchKernelGGL(gemm2_k, dim3(512), dim3(256), 0, stream,
                     h1T, w2b, stats1, g1, be1, o2, stats2);
  hipLaunchKernelGGL(final_k, dim3(512, 4, 4), dim3(32, 8), 0, stream,
                     o2, stats2, g2, be2, out);
}

// Round 18
// 230.895 us; speedup vs baseline: 1.0553x; 1.0553x over previous
//
#include <hip/hip_runtime.h>
#include <hip/hip_bf16.h>

#define INF_F (__builtin_inff())

typedef __attribute__((ext_vector_type(8))) short bf16x8;
typedef __attribute__((ext_vector_type(4))) float f32x4;

__device__ __forceinline__ unsigned short f2bf(float f) {
  __hip_bfloat16 h = __float2bfloat16(f);
  return __builtin_bit_cast(unsigned short, h);
}
__device__ __forceinline__ float bf2f(unsigned short u) {
  return __uint_as_float((unsigned)u << 16);
}

// branchy sorted top-3 insert (scalar state only - R8 lesson: nothing
// address-taken). Strict < + ascending s = top_k lowest-index tie order.
#define TOP3_INS(d, sj, E0, E1, E2, J0, J1, J2)                      \
  {                                                                  \
    bool l0 = (d) < E0, l1 = (d) < E1;                               \
    E2 = l1 ? E1 : (d); J2 = l1 ? J1 : (sj);                         \
    E1 = l0 ? E0 : (l1 ? (d) : E1); J1 = l0 ? J0 : (l1 ? (sj) : J1); \
    E0 = l0 ? (d) : E0; J0 = l0 ? (sj) : J0;                         \
  }

// ---------------------------------------------------------------------------
// B=4, N=16384, S=4096, D1=128, D2=256, MLP=(256,128). M = B*N = 65536.
// X: [65536][384] bf16 ; h1T: [65536][256] bf16 ; o2: [65536][128] bf16.
// GEMMs: D[c][n] = W[c][k] * X[n][k] via mfma_f32_16x16x32_bf16.
// R18 = R16 revert (best measured: 230.3us). R17's 128-thr knn blocks hit
// the ~8 workgroup/CU dispatch slot limit (occ 62%->40%, knn +20us):
// 256-thr x 8 slices x 2048 blocks is the confirmed local optimum.
// T14 async prep overlap in knnprep: loads ISSUE before knn loop (vmcnt in
// flight), knn runs on VALU + s_load (lgkmcnt), transpose+store after.
// ---------------------------------------------------------------------------

// pack sources (knn's only dependency) + zero BN stats accumulators.
// pack: [B][4096] float4 {x,y,z,|p|^2 or 3e38 if batch-id mismatch}.
__global__ __launch_bounds__(256) void pack_k(const float* __restrict__ xyz2,
                                              const int* __restrict__ idx1,
                                              const int* __restrict__ idx2,
                                              float4* __restrict__ pack,
                                              float* __restrict__ stats) {
  int id = blockIdx.x;
  int t = threadIdx.x;
  if (id < 64) {
    int pid = id * 256 + t;
    int b = pid >> 12, s = pid & 4095;
    float x = xyz2[(b * 3 + 0) * 4096 + s];
    float y = xyz2[(b * 3 + 1) * 4096 + s];
    float z = xyz2[(b * 3 + 2) * 4096 + s];
    float w = fmaf(x, x, fmaf(y, y, z * z));
    int common = idx1[b * 16384];
    w = (idx2[b * 4096 + s] == common) ? w : 3e38f;  // invalid -> wgt 0
    pack[b * 4096 + s] = make_float4(x, y, z, w);
  } else {
    for (int i = t; i < 768; i += 256) stats[i] = 0.f;
  }
}

// 3-NN stage 1 + T14-overlapped prep. 2048 blocks = 256 qgroups x 8 slices.
__global__ __launch_bounds__(256) void knnprep_k(const float* __restrict__ xyz1,
                                                 const float* __restrict__ xyz2,
                                                 const int* __restrict__ idx1,
                                                 const int* __restrict__ idx2,
                                                 const float4* __restrict__ pack,
                                                 const float* __restrict__ p2,
                                                 const float* __restrict__ p1,
                                                 const float* __restrict__ w1,
                                                 const float* __restrict__ w2,
                                                 unsigned short* __restrict__ p2t,
                                                 unsigned short* __restrict__ X,
                                                 unsigned short* __restrict__ w1b,
                                                 unsigned short* __restrict__ w2b,
                                                 float* __restrict__ rec) {
  __shared__ float tile[32][33];
  int bid = blockIdx.x;
  int t = threadIdx.x;
  int tx = t & 31, ty = t >> 5;
  // --- T14 stage A: ISSUE prep loads (no use -> no wait until stage C) ---
  float wv = 0.f;
  if (bid < 512) {
    int id3 = bid * 256 + t;
    wv = (id3 < 98304) ? w1[id3] : w2[id3 - 98304];
  }
  float t2r[2][4];  // 2 p2 tiles x 4 rows/thread
#pragma unroll
  for (int q = 0; q < 2; ++q) {
    int id = bid * 2 + q;
    int s0 = (id & 127) * 32;
    int k0 = ((id >> 7) & 7) * 32;
    int b = id >> 10;
    const float* src = p2 + ((size_t)b * 256 + k0) * 4096 + s0;
#pragma unroll
    for (int r4 = 0; r4 < 4; ++r4)
      t2r[q][r4] = src[(size_t)(ty + r4 * 8) * 4096 + tx];
  }
  float t1r[4][4];  // 4 p1 tiles x 4 rows/thread
#pragma unroll
  for (int q = 0; q < 4; ++q) {
    int id2 = bid * 4 + q;
    int n0 = (id2 & 511) * 32;
    int c0 = ((id2 >> 9) & 3) * 32;
    int b = id2 >> 11;
    const float* src = p1 + ((size_t)b * 128 + c0) * 16384 + n0;
#pragma unroll
    for (int r4 = 0; r4 < 4; ++r4)
      t1r[q][r4] = src[(size_t)(ty + r4 * 8) * 16384 + tx];
  }
  // --- T14 stage B: knn (VALU + s_load/lgkmcnt; vmem loads stay in flight) ---
  int qg = bid >> 3, sl = bid & 7;
  int b = qg >> 6;               // 64 query-groups per batch
  int nloc = (qg & 63) << 8;     // 256 queries per group
  int n = nloc + t;
  int q0i = b * 16384 + n;
  int common = idx1[b * 16384];
  int sbase = sl << 9;           // 512-source slice
  const float4* ps = pack + b * 4096 + sbase;
  float px = xyz1[(b * 3 + 0) * 16384 + n];
  float py = xyz1[(b * 3 + 1) * 16384 + n];
  float pz = xyz1[(b * 3 + 2) * 16384 + n];
  int myid = idx1[q0i];
  float pn = fmaf(px, px, fmaf(py, py, pz * pz));
  float qx = -2.f * px, qy = -2.f * py, qz = -2.f * pz;
  float e0 = INF_F, e1 = INF_F, e2 = INF_F;
  int j0 = 0, j1 = 0, j2 = 0;
#pragma unroll 8
  for (int s = 0; s < 512; ++s) {
    float4 p = ps[s];  // uniform addr -> scalar load (s_load_dwordx4/x16)
    float d = fmaf(qx, p.x, fmaf(qy, p.y, fmaf(qz, p.z, pn))) + p.w;
    if (__builtin_expect(d < e2, 0)) {  // 64 states/wave: genuinely skippable
      int sj = sbase + s;
      TOP3_INS(d, sj, e0, e1, e2, j0, j1, j2);
    }
  }
  if (__builtin_expect(myid != common, 0)) {  // exact general-idx fallback
    e0 = INF_F; e1 = INF_F; e2 = INF_F; j0 = 0; j1 = 0; j2 = 0;
    for (int s = 0; s < 512; ++s) {
      int gs = sbase + s;
      float x = xyz2[(b * 3 + 0) * 4096 + gs];
      float y = xyz2[(b * 3 + 1) * 4096 + gs];
      float z = xyz2[(b * 3 + 2) * 4096 + gs];
      float w = fmaf(x, x, fmaf(y, y, z * z));
      float d = fmaf(qx, x, fmaf(qy, y, fmaf(qz, z, pn))) + w;
      d = (idx2[b * 4096 + gs] == myid) ? d : INF_F;
      if (d < e2) TOP3_INS(d, gs, e0, e1, e2, j0, j1, j2);
    }
  }
  // rec layout [slice][query]: lane-consecutive 24B records => coalesced
  {
    float* r = &rec[((size_t)sl * 65536 + q0i) * 6];
    r[0] = e0; r[1] = e1; r[2] = e2;
    ((int*)r)[3] = j0; ((int*)r)[4] = j1; ((int*)r)[5] = j2;
  }
  // --- T14 stage C: write-late (vmcnt drains here; loads completed under B) ---
  if (bid < 512) {
    int id3 = bid * 256 + t;
    if (id3 < 98304) w1b[id3] = f2bf(wv);
    else w2b[id3 - 98304] = f2bf(wv);
  }
#pragma unroll
  for (int q = 0; q < 2; ++q) {
    int id = bid * 2 + q;
    int s0 = (id & 127) * 32;
    int k0 = ((id >> 7) & 7) * 32;
    int bb = id >> 10;
    __syncthreads();
#pragma unroll
    for (int r4 = 0; r4 < 4; ++r4) tile[ty + r4 * 8][tx] = t2r[q][r4];
    __syncthreads();
    unsigned short* dst = p2t + ((size_t)bb * 4096 + s0) * 256 + k0;
    for (int r = ty; r < 32; r += 8) dst[(size_t)r * 256 + tx] = f2bf(tile[tx][r]);
  }
#pragma unroll
  for (int q = 0; q < 4; ++q) {
    int id2 = bid * 4 + q;
    int n0 = (id2 & 511) * 32;
    int c0 = ((id2 >> 9) & 3) * 32;
    int bb = id2 >> 11;
    __syncthreads();
#pragma unroll
    for (int r4 = 0; r4 < 4; ++r4) tile[ty + r4 * 8][tx] = t1r[q][r4];
    __syncthreads();
    for (int r = ty; r < 32; r += 8)
      X[((size_t)(bb * 16384 + n0 + r)) * 384 + c0 + tx] = f2bf(tile[tx][r]);
  }
}

// fused: merge 8 S-slice records (lex (d,idx), ascending slice order = exact
// top_k ties) + inverse-distance weights + gather-interpolate into X.
// 512 blocks x 256 thr; block = 128 queries.
__global__ __launch_bounds__(256) void interpm_k(const float* __restrict__ rec,
                                                 const unsigned short* __restrict__ p2t,
                                                 unsigned short* __restrict__ X) {
  __shared__ int sId[128][3];
  __shared__ float sWt[128][3];
  int i0 = blockIdx.x * 128;
  int b = i0 >> 14;
  int t = threadIdx.x;
  if (t < 128) {
    int i = i0 + t;
    float e0, e1, e2;
    int j0, j1, j2;
    {
      const float* r = &rec[(size_t)i * 6];
      e0 = r[0]; e1 = r[1]; e2 = r[2];
      j0 = ((const int*)r)[3]; j1 = ((const int*)r)[4]; j2 = ((const int*)r)[5];
    }
#pragma unroll
    for (int c = 1; c < 8; ++c) {
      const float* r = &rec[((size_t)c * 65536 + i) * 6];
      const int* ir = (const int*)r;
#pragma unroll
      for (int w = 0; w < 3; ++w) {
        float d = r[w];
        int sj = ir[3 + w];
        bool l0 = (d < e0) || (d == e0 && sj < j0);
        bool l1 = (d < e1) || (d == e1 && sj < j1);
        bool l2 = (d < e2) || (d == e2 && sj < j2);
        e2 = l1 ? e1 : (l2 ? d : e2);
        j2 = l1 ? j1 : (l2 ? sj : j2);
        e1 = l0 ? e0 : (l1 ? d : e1);
        j1 = l0 ? j0 : (l1 ? sj : j1);
        e0 = l0 ? d : e0;
        j0 = l0 ? sj : j0;
      }
    }
    float r0 = 1.f / (e0 + 1e-8f);
    float r1 = 1.f / (e1 + 1e-8f);
    float r2 = 1.f / (e2 + 1e-8f);
    float rs = r0 + r1 + r2;
    sWt[t][0] = (e0 > 1e8f) ? 0.f : r0 / rs;  // ref: where(d3>BIG,0)+nan_to_num
    sWt[t][1] = (e1 > 1e8f) ? 0.f : r1 / rs;
    sWt[t][2] = (e2 > 1e8f) ? 0.f : r2 / rs;
    sId[t][0] = j0; sId[t][1] = j1; sId[t][2] = j2;
  }
  __syncthreads();
  int k = t;
  const unsigned short* base = p2t + (size_t)b * 4096 * 256;
#pragma unroll 2
  for (int ii = 0; ii < 128; ++ii) {
    int id0 = sId[ii][0], id1 = sId[ii][1], id2 = sId[ii][2];
    float w0 = sWt[ii][0], w1v = sWt[ii][1], w2v = sWt[ii][2];
    float v = w0 * bf2f(base[id0 * 256 + k]);
    v = fmaf(w1v, bf2f(base[id1 * 256 + k]), v);
    v = fmaf(w2v, bf2f(base[id2 * 256 + k]), v);
    X[(size_t)(i0 + ii) * 384 + 128 + k] = f2bf(v);
  }
}

// GEMM1 (MFMA): h1T[n][c] = sum_k w1[c][k] X[n][k]. 128x128 tile, BK=32,
// K=384. grid (512, 2). Epilogue: per-block BN1 stats (sum,sumsq per
// channel over block's 128 n) from fp32 acc -> atomicAdd into stats1[256][2].
__global__ __launch_bounds__(256) void gemm1_k(const unsigned short* __restrict__ X,
                                               const unsigned short* __restrict__ Wb,
                                               unsigned short* __restrict__ h1T,
                                               float* __restrict__ stats1) {
  __shared__ unsigned short sW[128][40];
  __shared__ unsigned short sX[128][40];
  int t = threadIdx.x;
  int i0 = blockIdx.x * 128;
  int c0 = blockIdx.y * 128;
  int w = t >> 6, lane = t & 63;
  int wc = (w & 1) * 64, wni = w >> 1;
  int wn = wni * 64;
  int l15 = lane & 15, g = lane >> 4;
  f32x4 acc[4][4];
#pragma unroll
  for (int a = 0; a < 4; ++a)
#pragma unroll
    for (int bq = 0; bq < 4; ++bq) acc[a][bq] = (f32x4)0.f;
  int sr = t & 127, sh = t >> 7;
  for (int kc = 0; kc < 12; ++kc) {
    int k0 = kc * 32;
    __syncthreads();
    {
      const uint4* gw = (const uint4*)&Wb[(size_t)(c0 + sr) * 384 + k0 + sh * 16];
      uint4 v0 = gw[0], v1 = gw[1];
      *(uint4*)&sW[sr][sh * 16] = v0;
      *(uint4*)&sW[sr][sh * 16 + 8] = v1;
      const uint4* gx = (const uint4*)&X[(size_t)(i0 + sr) * 384 + k0 + sh * 16];
      uint4 x0 = gx[0], x1 = gx[1];
      *(uint4*)&sX[sr][sh * 16] = x0;
      *(uint4*)&sX[sr][sh * 16 + 8] = x1;
    }
    __syncthreads();
    bf16x8 a[4], b[4];
#pragma unroll
    for (int tm = 0; tm < 4; ++tm)
      a[tm] = *(const bf16x8*)&sW[wc + tm * 16 + l15][g * 8];
#pragma unroll
    for (int tn = 0; tn < 4; ++tn)
      b[tn] = *(const bf16x8*)&sX[wn + tn * 16 + l15][g * 8];
#pragma unroll
    for (int tm = 0; tm < 4; ++tm)
#pragma unroll
      for (int tn = 0; tn < 4; ++tn)
        acc[tm][tn] = __builtin_amdgcn_mfma_f32_16x16x32_bf16(a[tm], b[tn], acc[tm][tn], 0, 0, 0);
  }
#pragma unroll
  for (int tm = 0; tm < 4; ++tm)
#pragma unroll
    for (int tn = 0; tn < 4; ++tn) {
      int c = c0 + wc + tm * 16 + g * 4;
      int n = i0 + wn + tn * 16 + l15;
      f32x4 v = acc[tm][tn];
      ushort4 o;
      o.x = f2bf(v[0]); o.y = f2bf(v[1]); o.z = f2bf(v[2]); o.w = f2bf(v[3]);
      *(ushort4*)&h1T[(size_t)n * 256 + c] = o;
    }
  // --- fused BN1 stats (fp32 acc) -> atomicAdd ---
  float s_[4][4], q_[4][4];
#pragma unroll
  for (int tm = 0; tm < 4; ++tm)
#pragma unroll
    for (int j = 0; j < 4; ++j) {
      float s = 0.f, q = 0.f;
#pragma unroll
      for (int tn = 0; tn < 4; ++tn) {
        float v = acc[tm][tn][j];
        s += v; q = fmaf(v, v, q);
      }
      s_[tm][j] = s; q_[tm][j] = q;
    }
#pragma unroll
  for (int mask = 1; mask < 16; mask <<= 1)
#pragma unroll
    for (int tm = 0; tm < 4; ++tm)
#pragma unroll
      for (int j = 0; j < 4; ++j) {
        s_[tm][j] += __shfl_xor(s_[tm][j], mask);
        q_[tm][j] += __shfl_xor(q_[tm][j], mask);
      }
  __syncthreads();                 // LDS reuse: sW as float red[2][128][2]
  float* red = (float*)&sW[0][0];
  if (l15 == 0) {
#pragma unroll
    for (int tm = 0; tm < 4; ++tm)
#pragma unroll
      for (int j = 0; j < 4; ++j) {
        int cl = wc + tm * 16 + g * 4 + j;
        red[(wni * 128 + cl) * 2 + 0] = s_[tm][j];
        red[(wni * 128 + cl) * 2 + 1] = q_[tm][j];
      }
  }
  __syncthreads();
  {
    int cl = t >> 1, st = t & 1;
    float v = red[(0 * 128 + cl) * 2 + st] + red[(1 * 128 + cl) * 2 + st];
    atomicAdd(&stats1[((c0 + cl) << 1) + st], v);
  }
}

// GEMM2 (MFMA). Prologue: fold stats1 -> per-channel BN1 a/c in LDS.
// Staging: BN1+relu fused. Epilogue: bf16 o2 write + BN2 stats atomicAdd.
__global__ __launch_bounds__(256) void gemm2_k(const unsigned short* __restrict__ h1T,
                                               const unsigned short* __restrict__ Wb,
                                               const float* __restrict__ stats1,
                                               const float* __restrict__ g1,
                                               const float* __restrict__ be1,
                                               unsigned short* __restrict__ o2,
                                               float* __restrict__ stats2) {
  __shared__ unsigned short sW[128][40];
  __shared__ unsigned short sX[128][40];
  __shared__ float sA1[256], sC1[256];
  int t = threadIdx.x;
  int i0 = blockIdx.x * 128;
  int w = t >> 6, lane = t & 63;
  int wc = (w & 1) * 64, wni = w >> 1;
  int wn = wni * 64;
  int l15 = lane & 15, g = lane >> 4;
  {  // fold BN1 (redundant per block; 256 ch, trivial)
    float s1v = stats1[t * 2 + 0], s2v = stats1[t * 2 + 1];
    float mean = s1v * (1.f / 65536.f);
    float var = s2v * (1.f / 65536.f) - mean * mean;  // biased, as torch BN
    float a = g1[t] * rsqrtf(var + 1e-5f);
    sA1[t] = a;
    sC1[t] = be1[t] - mean * a;
  }
  f32x4 acc[4][4];
#pragma unroll
  for (int a = 0; a < 4; ++a)
#pragma unroll
    for (int bq = 0; bq < 4; ++bq) acc[a][bq] = (f32x4)0.f;
  int sr = t & 127, sh = t >> 7;
  for (int kc = 0; kc < 8; ++kc) {
    int k0 = kc * 32;
    int kcol = k0 + sh * 16;
    __syncthreads();  // also covers prologue->staging dependency at kc=0
    {
      const uint4* gw = (const uint4*)&Wb[(size_t)sr * 256 + kcol];
      uint4 v0 = gw[0], v1 = gw[1];
      *(uint4*)&sW[sr][sh * 16] = v0;
      *(uint4*)&sW[sr][sh * 16 + 8] = v1;
      const uint4* gx = (const uint4*)&h1T[(size_t)(i0 + sr) * 256 + kcol];
      uint4 x0 = gx[0], x1 = gx[1];
      unsigned rr[8] = {x0.x, x0.y, x0.z, x0.w, x1.x, x1.y, x1.z, x1.w};
      unsigned ww[8];
#pragma unroll
      for (int e = 0; e < 8; ++e) {  // BN1+relu fused while staging
        int ch = kcol + 2 * e;
        float f0 = bf2f((unsigned short)(rr[e] & 0xFFFFu));
        float f1 = bf2f((unsigned short)(rr[e] >> 16));
        f0 = fmaxf(fmaf(sA1[ch], f0, sC1[ch]), 0.f);
        f1 = fmaxf(fmaf(sA1[ch + 1], f1, sC1[ch + 1]), 0.f);
        ww[e] = (unsigned)f2bf(f0) | ((unsigned)f2bf(f1) << 16);
      }
      uint4 y0 = {ww[0], ww[1], ww[2], ww[3]};
      uint4 y1 = {ww[4], ww[5], ww[6], ww[7]};
      *(uint4*)&sX[sr][sh * 16] = y0;
      *(uint4*)&sX[sr][sh * 16 + 8] = y1;
    }
    __syncthreads();
    bf16x8 a[4], b[4];
#pragma unroll
    for (int tm = 0; tm < 4; ++tm)
      a[tm] = *(const bf16x8*)&sW[wc + tm * 16 + l15][g * 8];
#pragma unroll
    for (int tn = 0; tn < 4; ++tn)
      b[tn] = *(const bf16x8*)&sX[wn + tn * 16 + l15][g * 8];
#pragma unroll
    for (int tm = 0; tm < 4; ++tm)
#pragma unroll
      for (int tn = 0; tn < 4; ++tn)
        acc[tm][tn] = __builtin_amdgcn_mfma_f32_16x16x32_bf16(a[tm], b[tn], acc[tm][tn], 0, 0, 0);
  }
#pragma unroll
  for (int tm = 0; tm < 4; ++tm)
#pragma unroll
    for (int tn = 0; tn < 4; ++tn) {
      int c = wc + tm * 16 + g * 4;
      int n = i0 + wn + tn * 16 + l15;
      f32x4 v = acc[tm][tn];
      ushort4 o;
      o.x = f2bf(v[0]); o.y = f2bf(v[1]); o.z = f2bf(v[2]); o.w = f2bf(v[3]);
      *(ushort4*)&o2[(size_t)n * 128 + c] = o;
    }
  // --- fused BN2 stats (fp32 acc) -> atomicAdd ---
  float s_[4][4], q_[4][4];
#pragma unroll
  for (int tm = 0; tm < 4; ++tm)
#pragma unroll
    for (int j = 0; j < 4; ++j) {
      float s = 0.f, q = 0.f;
#pragma unroll
      for (int tn = 0; tn < 4; ++tn) {
        float v = acc[tm][tn][j];
        s += v; q = fmaf(v, v, q);
      }
      s_[tm][j] = s; q_[tm][j] = q;
    }
#pragma unroll
  for (int mask = 1; mask < 16; mask <<= 1)
#pragma unroll
    for (int tm = 0; tm < 4; ++tm)
#pragma unroll
      for (int j = 0; j < 4; ++j) {
        s_[tm][j] += __shfl_xor(s_[tm][j], mask);
        q_[tm][j] += __shfl_xor(q_[tm][j], mask);
      }
  __syncthreads();
  float* red = (float*)&sW[0][0];  // [2][128][2]
  if (l15 == 0) {
#pragma unroll
    for (int tm = 0; tm < 4; ++tm)
#pragma unroll
      for (int j = 0; j < 4; ++j) {
        int cl = wc + tm * 16 + g * 4 + j;
        red[(wni * 128 + cl) * 2 + 0] = s_[tm][j];
        red[(wni * 128 + cl) * 2 + 1] = q_[tm][j];
      }
  }
  __syncthreads();
  {
    int cl = t >> 1, st = t & 1;
    float v = red[(0 * 128 + cl) * 2 + st] + red[(1 * 128 + cl) * 2 + st];
    atomicAdd(&stats2[(cl << 1) + st], v);
  }
}

// final: fold stats2 -> BN2 a/c, apply + relu, transpose o2 bf16 [i][128]
// -> d_out [B][128][16384] fp32.
__global__ __launch_bounds__(256) void final_k(const unsigned short* __restrict__ o2,
                                               const float* __restrict__ stats2,
                                               const float* __restrict__ g2,
                                               const float* __restrict__ be2,
                                               float* __restrict__ out) {
  __shared__ float tile[32][33];
  __shared__ float sA2[128], sC2[128];
  int b = blockIdx.z;
  int n0 = blockIdx.x * 32;
  int c0 = blockIdx.y * 32;
  int tx = threadIdx.x, ty = threadIdx.y;
  int tid = ty * 32 + tx;
  if (tid < 128) {  // fold BN2 (redundant per block; 128 ch, trivial)
    float s1v = stats2[tid * 2 + 0], s2v = stats2[tid * 2 + 1];
    float mean = s1v * (1.f / 65536.f);
    float var = s2v * (1.f / 65536.f) - mean * mean;  // biased, as torch BN
    float a = g2[tid] * rsqrtf(var + 1e-5f);
    sA2[tid] = a;
    sC2[tid] = be2[tid] - mean * a;
  }
  __syncthreads();
  float a = sA2[c0 + tx], cc = sC2[c0 + tx];
  for (int r = ty; r < 32; r += 8) {
    float v = bf2f(o2[(size_t)(b * 16384 + n0 + r) * 128 + c0 + tx]);
    tile[r][tx] = fmaxf(fmaf(a, v, cc), 0.f);
  }
  __syncthreads();
  for (int r = ty; r < 32; r += 8)
    out[((size_t)(b * 128 + c0 + r)) * 16384 + n0 + tx] = tile[tx][r];
}

extern "C" void kernel_launch(void* const* d_in, const int* in_sizes, int n_in,
                              void* d_out, int out_size, void* d_ws, size_t ws_size,
                              hipStream_t stream) {
  const float* xyz1 = (const float*)d_in[0];
  const float* xyz2 = (const float*)d_in[1];
  const float* p1   = (const float*)d_in[2];
  const float* p2   = (const float*)d_in[3];
  const int*   idx1 = (const int*)d_in[4];
  const int*   idx2 = (const int*)d_in[5];
  const float* w1   = (const float*)d_in[6];
  // d_in[7]=b1, d_in[11]=b2: exactly absorbed by BN mean subtraction
  const float* g1   = (const float*)d_in[8];
  const float* be1  = (const float*)d_in[9];
  const float* w2   = (const float*)d_in[10];
  const float* g2   = (const float*)d_in[12];
  const float* be2  = (const float*)d_in[13];
  float* out = (float*)d_out;

  char* ws = (char*)d_ws;
  // X 48MB | h1T 32MB (p2t bf16 8.4MB aliased: dead before gemm1 writes)
  // | o2 bf16 16MB (rec 12.6MB aliased: dead before gemm2 writes) | w1b w2b
  // | pack 262KB | stats 3KB  => ~98MB
  unsigned short* X    = (unsigned short*)(ws + 0x180000);      // 48MB
  unsigned short* h1T  = (unsigned short*)(ws + 0x3180000);     // 32MB
  unsigned short* p2t  = (unsigned short*)(ws + 0x3180000);     // alias h1T
  unsigned short* o2   = (unsigned short*)(ws + 0x5180000);     // 16MB
  float*          rec  = (float*)(ws + 0x5180000);              // alias o2
  unsigned short* w1b  = (unsigned short*)(ws + 0x7180000);
  unsigned short* w2b  = (unsigned short*)(ws + 0x71B0000);
  float4*         pack = (float4*)(ws + 0x71C0000);             // 262KB
  float*          stats = (float*)(ws + 0x7208000);             // 768 floats
  float*          stats1 = stats;                               // [256][2]
  float*          stats2 = stats + 512;                         // [128][2]

  hipLaunchKernelGGL(pack_k, dim3(65), dim3(256), 0, stream,
                     xyz2, idx1, idx2, pack, stats);
  hipLaunchKernelGGL(knnprep_k, dim3(2048), dim3(256), 0, stream,
                     xyz1, xyz2, idx1, idx2, pack, p2, p1, w1, w2,
                     p2t, X, w1b, w2b, rec);
  hipLaunchKernelGGL(interpm_k, dim3(512), dim3(256), 0, stream, rec, p2t, X);
  hipLaunchKernelGGL(gemm1_k, dim3(512, 2), dim3(256), 0, stream, X, w1b, h1T, stats1);
  hipLaunchKernelGGL(gemm2_k, dim3(512), dim3(256), 0, stream,
                     h1T, w2b, stats1, g1, be1, o2, stats2);
  hipLaunchKernelGGL(final_k, dim3(512, 4, 4), dim3(32, 8), 0, stream,
                     o2, stats2, g2, be2, out);
}